// Round 20
// baseline (16.746 us; speedup 1.0000x reference)
//
#include <hip/hip_runtime.h>
#include <math.h>

// RKN cell: B=4096, LOD=64, LSD=128, H=64, NB=15, NE=436 (band +-3)
// R20: R19 with B2/B3 ELIMINATED: waves 0-3 each compute the FULL MLP
// (redundant 4x col-tiles) into wave-private LDS h-buffers (intra-wave
// lgkmcnt dependency, no __syncthreads); waves 4-15 stage all basis planes
// in one stretch. Barriers 5 -> 3. Numerics identical to R16/R19.
#define O_PM   0
#define O_PCU  524288
#define O_PCL  786432
#define O_PCS  1048576
#define O_NM   1310720
#define O_NCU  1835008
#define O_NCL  2097152
#define O_NCS  2359296

// ---- LDS word map (39072 words = 156288 B, 1 block/CU) ----
// union [0,8384): W1L[64][76] | W2L@4864 [64][44] | W3L@7680 [16][44]
//   -> tm u16 [16 r][1748] after B4 (13984 words)
// BAST [13984,27968): [8 kp][1748] u32 bf16-pairs
// PMB  [27968,29184): bf16 pairs [16][76]
// HP   [29184,33792): 4 waves x {h1,h2} private, each [16 r][72 u16] (576 w)
// COEF [33792,33952): u16 [16 r][20]
// PMF  [33952,36000): f32 [16][128]; CUF/CLF/CSF: f32 [16][64] each
#define TM_S   1748
#define L_W1   0
#define L_W2   4864
#define L_W3   7680
#define L_TM   0
#define L_BAST 13984
#define L_PMB  27968
#define L_HP   29184
#define L_COEF 33792
#define L_PMF  33952
#define L_CUF  36000
#define L_CLF  37024
#define L_CSF  38048
#define L_TOT  39072

typedef short s8v __attribute__((ext_vector_type(8)));
typedef short s4v __attribute__((ext_vector_type(4)));
typedef float f4v __attribute__((ext_vector_type(4)));

__device__ __forceinline__ unsigned pk2(float a, float b) {   // 2xf32 -> 2xbf16 RNE
    unsigned ua = __float_as_uint(a), ub = __float_as_uint(b);
    ua += 0x7fffu + ((ua >> 16) & 1u);
    ub += 0x7fffu + ((ub >> 16) & 1u);
    return (ua >> 16) | (ub & 0xffff0000u);
}
__device__ __forceinline__ unsigned short tobf(float a) {
    unsigned ua = __float_as_uint(a);
    ua += 0x7fffu + ((ua >> 16) & 1u);
    return (unsigned short)(ua >> 16);
}
__device__ __forceinline__ float frombf(unsigned short u) {
    return __uint_as_float(((unsigned)u) << 16);
}
__device__ __forceinline__ float lo16(unsigned w) { return __uint_as_float(w << 16); }
__device__ __forceinline__ float hi16(unsigned w) { return __uint_as_float(w & 0xffff0000u); }
__device__ __forceinline__ float frcp(float x) { return __builtin_amdgcn_rcpf(x); }
__device__ __forceinline__ float ftanh(float x) {
    float e = __expf(2.f * x);
    return 1.f - 2.f * frcp(e + 1.f);
}
#define SWZ(v, imm) __uint_as_float((unsigned)__builtin_amdgcn_ds_swizzle((int)__float_as_uint(v), imm))

#if __has_builtin(__builtin_amdgcn_mfma_f32_16x16x16_bf16)
#define MFMA16(A,B,C) __builtin_amdgcn_mfma_f32_16x16x16_bf16(A,B,C,0,0,0)
#elif __has_builtin(__builtin_amdgcn_mfma_f32_16x16x16bf16_1k)
#define MFMA16(A,B,C) __builtin_amdgcn_mfma_f32_16x16x16bf16_1k(A,B,C,0,0,0)
#else
// Host-pass stub only; device pass resolves a real branch (R11-R19 proven).
#define MFMA16(A,B,C) (C)
#endif

#if __has_builtin(__builtin_amdgcn_s_setprio)
#define SETPRIO(n) __builtin_amdgcn_s_setprio(n)
#else
#define SETPRIO(n)
#endif

__global__ __launch_bounds__(1024, 4)
void rkn_kernel(const float* __restrict__ prior_mean,
                const float* __restrict__ cov_u,
                const float* __restrict__ cov_l,
                const float* __restrict__ cov_s,
                const float* __restrict__ obs,
                const float* __restrict__ obs_var,
                const float* __restrict__ W1,
                const float* __restrict__ b1,
                const float* __restrict__ W2,
                const float* __restrict__ b2,
                const float* __restrict__ W3,
                const float* __restrict__ b3,
                const float* __restrict__ tm11b,
                const float* __restrict__ tm12b,
                const float* __restrict__ tm21b,
                const float* __restrict__ tm22b,
                const float* __restrict__ ltn,
                float* __restrict__ out)
{
    __shared__ __align__(16) unsigned smem[L_TOT];

    const int tid  = threadIdx.x;
    const int wid  = tid >> 6;      // 0..15
    const int lane = tid & 63;
    const int lrow = lane & 15;     // MFMA operand row (A row / B col)
    const int lkg  = lane >> 4;     // k-group

    // ---- stage weights: coalesced float4 reads, bf16-pair LDS writes ----
    {
#pragma unroll
        for (int it = 0; it < 2; ++it) {              // W1: 2048 float4
            const int idx = it * 1024 + tid;
            const float4 v = ((const float4*)W1)[idx];
            const int j = idx >> 5, kq = idx & 31;
            unsigned* d = smem + (L_W1 + j * 76 + kq * 2);
            d[0] = pk2(v.x, v.y); d[1] = pk2(v.z, v.w);
        }
        {                                             // W2: 1024 float4
            const int idx = tid;
            const float4 v = ((const float4*)W2)[idx];
            const int j = idx >> 4, kq = idx & 15;
            unsigned* d = smem + (L_W2 + j * 44 + kq * 2);
            d[0] = pk2(v.x, v.y); d[1] = pk2(v.z, v.w);
        }
        if (tid < 240) {                              // W3: 15 j x 16 float4
            const float4 v = ((const float4*)W3)[tid];
            const int j = tid >> 4, kq = tid & 15;
            unsigned* d = smem + (L_W3 + j * 44 + kq * 2);
            d[0] = pk2(v.x, v.y); d[1] = pk2(v.z, v.w);
        } else if (tid < 284) {                       // zero W3 row 15
            smem[L_W3 + 15 * 44 + (tid - 240)] = 0u;
        }
    }

    // ---- phase 1: Kalman on tid<512 (row = tid>>5, dims pd,pd+1) ----
    if (tid < 512) {
        const int prow  = tid >> 5;
        const int pd    = (tid & 31) << 1;
        const int grow1 = blockIdx.x * 16 + prow;
        const float2 cu2 = *(const float2*)(cov_u   + grow1 * 64 + pd);
        const float2 cl2 = *(const float2*)(cov_l   + grow1 * 64 + pd);
        const float2 cs2 = *(const float2*)(cov_s   + grow1 * 64 + pd);
        const float2 ob2 = *(const float2*)(obs     + grow1 * 64 + pd);
        const float2 ov2 = *(const float2*)(obs_var + grow1 * 64 + pd);
        const float2 pu2 = *(const float2*)(prior_mean + grow1 * 128 + pd);
        const float2 pl2 = *(const float2*)(prior_mean + grow1 * 128 + 64 + pd);

        const float i0 = frcp(cu2.x + ov2.x), i1 = frcp(cu2.y + ov2.y);
        const float qu0 = cu2.x * i0, qu1 = cu2.y * i1;
        const float ql0 = cs2.x * i0, ql1 = cs2.y * i1;
        const float r0 = ob2.x - pu2.x, r1 = ob2.y - pu2.y;
        const float pmu0 = pu2.x + qu0 * r0, pmu1 = pu2.y + qu1 * r1;
        const float pml0 = pl2.x + ql0 * r0, pml1 = pl2.y + ql1 * r1;
        const float cf0 = 1.f - qu0, cf1 = 1.f - qu1;
        const float pcu0 = cf0 * cu2.x, pcu1 = cf1 * cu2.y;
        const float pcl0 = cl2.x - ql0 * cs2.x, pcl1 = cl2.y - ql1 * cs2.y;
        const float pcs0 = cf0 * cs2.x, pcs1 = cf1 * cs2.y;

        *(float2*)(out + O_PM  + grow1 * 128 + pd)      = make_float2(pmu0, pmu1);
        *(float2*)(out + O_PM  + grow1 * 128 + 64 + pd) = make_float2(pml0, pml1);
        *(float2*)(out + O_PCU + grow1 * 64 + pd) = make_float2(pcu0, pcu1);
        *(float2*)(out + O_PCL + grow1 * 64 + pd) = make_float2(pcl0, pcl1);
        *(float2*)(out + O_PCS + grow1 * 64 + pd) = make_float2(pcs0, pcs1);

        smem[L_PMB + prow * 76 + (pd >> 1)]      = pk2(pmu0, pmu1);
        smem[L_PMB + prow * 76 + 32 + (pd >> 1)] = pk2(pml0, pml1);
        *(float2*)((float*)(smem + L_PMF) + prow * 128 + pd)      = make_float2(pmu0, pmu1);
        *(float2*)((float*)(smem + L_PMF) + prow * 128 + 64 + pd) = make_float2(pml0, pml1);
        *(float2*)((float*)(smem + L_CUF) + prow * 64 + pd) = make_float2(pcu0, pcu1);
        *(float2*)((float*)(smem + L_CLF) + prow * 64 + pd) = make_float2(pcl0, pcl1);
        *(float2*)((float*)(smem + L_CSF) + prow * 64 + pd) = make_float2(pcs0, pcs1);
    }

    // softplus(trans noise) for phase 4 (per lane)
    const float tcu = __logf(__expf(ltn[lane]) + 1.f);
    const float tcl = __logf(__expf(ltn[64 + lane]) + 1.f);

    __syncthreads();   // B1: weights + pm staged

    // ==== waves 0-3: FULL MLP (redundant, private h buffers, no barriers)
    // ==== waves 4-15: stage all 8 basisT planes in one stretch
    const int t2 = tid - 256;                  // valid for wid>=4: 0..767
    const int ms = t2 & 3;
    const float* bps = (ms == 0) ? tm11b : (ms == 1) ? tm12b : (ms == 2) ? tm21b : tm22b;

    if (wid < 4) {
        SETPRIO(1);
        unsigned short* h1p = (unsigned short*)(smem + L_HP + wid * 1152);
        unsigned short* h2p = (unsigned short*)(smem + L_HP + wid * 1152 + 576);

        // layer 1: K=128, all 4 col-tiles
#pragma unroll
        for (int ct = 0; ct < 4; ++ct) {
            f4v acc = {0.f, 0.f, 0.f, 0.f};
#pragma unroll
            for (int s = 0; s < 4; ++s) {
                s8v a = *(const s8v*)(smem + L_PMB + lrow * 76 + s * 16 + lkg * 4);
                s8v b = *(const s8v*)(smem + L_W1 + (ct * 16 + lrow) * 76 + s * 16 + lkg * 4);
                acc = __builtin_amdgcn_mfma_f32_16x16x32_bf16(a, b, acc, 0, 0, 0);
            }
            const float bc = b1[ct * 16 + lrow];
#pragma unroll
            for (int q = 0; q < 4; ++q)
                h1p[(lkg * 4 + q) * 72 + ct * 16 + lrow] = tobf(ftanh(acc[q] + bc));
        }
        // layer 2: K=64, all 4 col-tiles (intra-wave dependency on h1p)
#pragma unroll
        for (int ct = 0; ct < 4; ++ct) {
            f4v acc = {0.f, 0.f, 0.f, 0.f};
#pragma unroll
            for (int s = 0; s < 2; ++s) {
                s8v a = *(const s8v*)(h1p + lrow * 72 + s * 32 + lkg * 8);
                s8v b = *(const s8v*)(smem + L_W2 + (ct * 16 + lrow) * 44 + s * 16 + lkg * 4);
                acc = __builtin_amdgcn_mfma_f32_16x16x32_bf16(a, b, acc, 0, 0, 0);
            }
            const float bc = b2[ct * 16 + lrow];
#pragma unroll
            for (int q = 0; q < 4; ++q)
                h2p[(lkg * 4 + q) * 72 + ct * 16 + lrow] = tobf(ftanh(acc[q] + bc));
        }
        // layer 3: K=64, cols 0-14 only
        {
            f4v acc = {0.f, 0.f, 0.f, 0.f};
#pragma unroll
            for (int s = 0; s < 2; ++s) {
                s8v a = *(const s8v*)(h2p + lrow * 72 + s * 32 + lkg * 8);
                s8v b = *(const s8v*)(smem + L_W3 + lrow * 44 + s * 16 + lkg * 4);
                acc = __builtin_amdgcn_mfma_f32_16x16x32_bf16(a, b, acc, 0, 0, 0);
            }
            const float bc3 = (lrow < 15) ? b3[lrow] : 0.f;
            unsigned short* cfu = (unsigned short*)(smem + L_COEF);
#pragma unroll
            for (int q = 0; q < 4; ++q) {             // in-frag softmax over cols
                const float lg = acc[q] + bc3;
                float v = (lrow < 15) ? lg : -1e30f;
                v = fmaxf(v, SWZ(v, 0x041F));
                v = fmaxf(v, SWZ(v, 0x081F));
                v = fmaxf(v, SWZ(v, 0x101F));
                v = fmaxf(v, SWZ(v, 0x201F));
                const float ex = (lrow < 15) ? __expf(lg - v) : 0.f;
                float ss = ex;
                ss += SWZ(ss, 0x041F);
                ss += SWZ(ss, 0x081F);
                ss += SWZ(ss, 0x101F);
                ss += SWZ(ss, 0x201F);
                if (wid == 0)
                    cfu[(lkg * 4 + q) * 20 + lrow] = tobf(ex * frcp(ss));
            }
        }
        SETPRIO(0);
    } else {
        // waves 4-15: stage basisT planes kp 0-7, one uninterrupted stretch
#pragma unroll
        for (int kp = 0; kp < 8; ++kp)
#pragma unroll
            for (int c = 0; c < 3; ++c) {
                const int n = c * 768 + t2;
                if (n < 1744) {
                    const int e = n >> 2;
                    const float lo = bps[(2 * kp) * 436 + e];
                    const float hi = (kp < 7) ? bps[(2 * kp + 1) * 436 + e] : 0.f;
                    smem[L_BAST + kp * TM_S + n] = pk2(lo, hi);
                }
            }
    }
    __syncthreads();   // B4: coeff + basisT ready; weights dead -> tm region

    // ---- phase 3: tm[16][1744] = coeff[16][15] . basisT (MFMA, 16 waves) ----
    {
        unsigned short* tmu = (unsigned short*)(smem + L_TM);
        const s4v ca = *(const s4v*)(smem + L_COEF + lrow * 10 + lkg * 2);
#pragma unroll
        for (int i = 0; i < 7; ++i) {
            const int t = i * 16 + wid;
            if (t < 109) {
                const int nn = t * 16 + lrow;
                unsigned wpair[2];
                wpair[0] = smem[L_BAST + (lkg * 2    ) * TM_S + nn];
                wpair[1] = smem[L_BAST + (lkg * 2 + 1) * TM_S + nn];
                const s4v bb = *(const s4v*)wpair;
                f4v d = {0.f, 0.f, 0.f, 0.f};
                d = MFMA16(ca, bb, d);
#pragma unroll
                for (int q = 0; q < 4; ++q)
                    tmu[(lkg * 4 + q) * TM_S + nn] = tobf(d[q]);
            }
        }
    }
    __syncthreads();   // B5: tm visible

    // ---- phase 4: banded mat-vec combos; wave = row ----
    {
        const int i   = lane;
        const int jlo = (i - 3 > 0) ? (i - 3) : 0;
        const int ne  = ((i + 3 < 63) ? (i + 3) : 63) - jlo + 1;
        const int base = (i < 4)  ? (i * (i + 7)) / 2
                       : (i <= 61) ? (7 * i - 6)
                       : (i == 62) ? 427 : 432;
        const float* pmf = (const float*)(smem + L_PMF);
        const float* cuf = (const float*)(smem + L_CUF);
        const float* clf = (const float*)(smem + L_CLF);
        const float* csf = (const float*)(smem + L_CSF);
        const uint2* tmr = (const uint2*)smem;   // tm: uint2 idx r*(TM_S/4)+e

        const int r  = wid;
        const int gr = blockIdx.x * 16 + r;
        float nmu = 0.f, nml = 0.f, ncu = 0.f, ncl = 0.f, ncs = 0.f;
#pragma unroll
        for (int dd = 0; dd < 7; ++dd) {
            if (dd < ne) {
                const int j = jlo + dd;
                const uint2 tv = tmr[r * (TM_S / 4) + base + dd];
                float t11 = lo16(tv.x);
                float t12 = hi16(tv.x);
                float t21 = lo16(tv.y);
                float t22 = hi16(tv.y);
                if (j == i) { t11 += 1.f; t22 += 1.f; }
                const float mu  = pmf[r * 128 + j];
                const float ml  = pmf[r * 128 + 64 + j];
                const float vcu = cuf[r * 64 + j];
                const float vcl = clf[r * 64 + j];
                const float vcs = csf[r * 64 + j];
                nmu += t11 * mu + t12 * ml;
                nml += t21 * mu + t22 * ml;
                ncu += t11 * t11 * vcu + 2.f * t11 * t12 * vcs + t12 * t12 * vcl;
                ncl += t21 * t21 * vcu + 2.f * t21 * t22 * vcs + t22 * t22 * vcl;
                ncs += t21 * t11 * vcu + (t22 * t11 + t21 * t12) * vcs + t22 * t12 * vcl;
            }
        }
        out[O_NM  + gr * 128 + i]      = nmu;
        out[O_NM  + gr * 128 + 64 + i] = nml;
        out[O_NCU + gr * 64 + i] = ncu + tcu;
        out[O_NCL + gr * 64 + i] = ncl + tcl;
        out[O_NCS + gr * 64 + i] = ncs;
    }
}

extern "C" void kernel_launch(void* const* d_in, const int* in_sizes, int n_in,
                              void* d_out, int out_size, void* d_ws, size_t ws_size,
                              hipStream_t stream) {
    rkn_kernel<<<dim3(256), dim3(1024), 0, stream>>>(
        (const float*)d_in[0],  // prior_mean
        (const float*)d_in[1],  // cov_u
        (const float*)d_in[2],  // cov_l
        (const float*)d_in[3],  // cov_s
        (const float*)d_in[4],  // obs
        (const float*)d_in[5],  // obs_var
        (const float*)d_in[6],  // W1
        (const float*)d_in[7],  // b1
        (const float*)d_in[8],  // W2
        (const float*)d_in[9],  // b2
        (const float*)d_in[10], // W3
        (const float*)d_in[11], // b3
        (const float*)d_in[12], // tm11_basis
        (const float*)d_in[13], // tm12_basis
        (const float*)d_in[14], // tm21_basis
        (const float*)d_in[15], // tm22_basis
        (const float*)d_in[16], // log_trans_noise
        (float*)d_out);
}